// Round 1
// 303.706 us; speedup vs baseline: 1.0894x; 1.0894x over previous
//
#include <hip/hip_runtime.h>
#include <hip/hip_bf16.h>

#define N_NODES 100000
#define N_EDGES 1600000
#define D 128
#define SCAN_N (N_NODES + 1)   // 100001

// Radix-style CSR build parameters
#define NBLK 256                // edge-partition blocks
#define EPB (N_EDGES / NBLK)    // 6250 edges per block
#define BROWS 128               // rows per bucket
#define NB 782                  // ceil(N_NODES / BROWS)
#define SCANB_N (NB * NBLK)     // 200192
#define SCANB_BLOCKS 196        // 196*1024 = 200704 >= SCANB_N + 1
#define K4_CAP 8192             // max staged edges per bucket (mean 2046, +130 sigma)

typedef __attribute__((ext_vector_type(8))) short short8;
typedef __attribute__((ext_vector_type(4))) float f32x4;

__device__ inline unsigned short f2bf(float f) {
  union { float f; unsigned u; } c; c.f = f;
  const unsigned u = c.u;
  return (unsigned short)((u + 0x7FFF + ((u >> 16) & 1)) >> 16);  // RNE
}
__device__ inline float bflo(unsigned u) { return __int_as_float(u << 16); }
__device__ inline float bfhi(unsigned u) { return __int_as_float(u & 0xFFFF0000u); }

// ---------------------------------------------------------------------------
// GEMM (bf16 MFMA): support[n][j] = bf16((x@W + lin_bias)[n][j]), row-major.
// 128 rows/block, 256 threads (4 waves).
// ---------------------------------------------------------------------------
#define GR 128
#define LDK 136
__global__ __launch_bounds__(256) void gemm_kernel(
    const float* __restrict__ x, const float* __restrict__ W,
    const float* __restrict__ lin_bias, unsigned short* __restrict__ support) {
  __shared__ unsigned short Wt[128 * LDK];  // W transposed: Wt[n][k]
  __shared__ unsigned short xb[GR * LDK];   // xb[r][k]
  const int t = threadIdx.x;
  const int row0 = blockIdx.x * GR;

  for (int i = t; i < 128 * 32; i += 256) {
    const int k = i >> 5, n4 = (i & 31) * 4;
    const float4 w = *(const float4*)(W + k * D + n4);
    Wt[(n4 + 0) * LDK + k] = f2bf(w.x);
    Wt[(n4 + 1) * LDK + k] = f2bf(w.y);
    Wt[(n4 + 2) * LDK + k] = f2bf(w.z);
    Wt[(n4 + 3) * LDK + k] = f2bf(w.w);
  }
  for (int i = t; i < GR * 32; i += 256) {
    const int r = i >> 5, k4 = (i & 31) * 4;
    const int row = row0 + r;
    float4 v = make_float4(0.f, 0.f, 0.f, 0.f);
    if (row < N_NODES) v = *(const float4*)(x + (size_t)row * D + k4);
    unsigned short* p = &xb[r * LDK + k4];
    p[0] = f2bf(v.x); p[1] = f2bf(v.y); p[2] = f2bf(v.z); p[3] = f2bf(v.w);
  }
  __syncthreads();

  const int w = t >> 6;
  const int lane = t & 63;
  const int m16 = lane & 15;
  const int quad = lane >> 4;

  f32x4 acc[2][8];
#pragma unroll
  for (int rt = 0; rt < 2; ++rt)
#pragma unroll
    for (int ct = 0; ct < 8; ++ct) acc[rt][ct] = (f32x4){0.f, 0.f, 0.f, 0.f};

#pragma unroll
  for (int kc = 0; kc < 4; ++kc) {
    const int kof = kc * 32 + quad * 8;
    short8 a0 = *(const short8*)&xb[(w * 32 + 0 * 16 + m16) * LDK + kof];
    short8 a1 = *(const short8*)&xb[(w * 32 + 1 * 16 + m16) * LDK + kof];
#pragma unroll
    for (int ct = 0; ct < 8; ++ct) {
      const short8 b = *(const short8*)&Wt[(ct * 16 + m16) * LDK + kof];
      acc[0][ct] = __builtin_amdgcn_mfma_f32_16x16x32_bf16(a0, b, acc[0][ct], 0, 0, 0);
      acc[1][ct] = __builtin_amdgcn_mfma_f32_16x16x32_bf16(a1, b, acc[1][ct], 0, 0, 0);
    }
  }

  // Epilogue: C/D layout col=lane&15, row=quad*4+reg. Row-major bf16 stores.
#pragma unroll
  for (int ct = 0; ct < 8; ++ct) {
    const int col = ct * 16 + m16;
    const float lb = lin_bias[col];
#pragma unroll
    for (int rt = 0; rt < 2; ++rt) {
      const int rbase = row0 + w * 32 + rt * 16 + quad * 4;
#pragma unroll
      for (int i = 0; i < 4; ++i) {
        const int row = rbase + i;
        if (row < N_NODES)
          support[(size_t)row * D + col] = f2bf(acc[rt][ct][i] + lb);
      }
    }
  }
}

// ---------------------------------------------------------------------------
// CSR build, no global atomics:
//   bhist   : per-block LDS histogram over NB buckets -> bcount[b][blk]
//   bscanA/B: exclusive scan of bcount (200192 elements) -> boffs
//   bscatter: LDS cursors give rank; write bucket-grouped pairs + rowlo
//   rowsort : per-bucket LDS counting sort by local row; in-place rewrite of
//             pairs into row-sorted order; emits row_start.
// ---------------------------------------------------------------------------
__global__ __launch_bounds__(256) void bhist_kernel(
    const int* __restrict__ rows, int* __restrict__ bcount) {
  __shared__ int cnt[NB];
  const int t = threadIdx.x, blk = blockIdx.x;
  for (int i = t; i < NB; i += 256) cnt[i] = 0;
  __syncthreads();
  const int base = blk * EPB;
  for (int i = t; i < EPB; i += 256) {
    const int r = rows[base + i];
    atomicAdd(&cnt[r >> 7], 1);     // LDS atomic only
  }
  __syncthreads();
  for (int i = t; i < NB; i += 256) bcount[i * NBLK + blk] = cnt[i];
}

// Inclusive scan of shifted bcount => exclusive offsets boffs.
__global__ __launch_bounds__(1024) void bscanA_kernel(
    const int* __restrict__ bcount, int* __restrict__ boffs,
    int* __restrict__ partials) {
  __shared__ int s[1024];
  const int t = threadIdx.x;
  const int i = blockIdx.x * 1024 + t;
  int v = 0;
  if (i >= 1 && i <= SCANB_N) v = bcount[i - 1];
  s[t] = v;
  __syncthreads();
#pragma unroll
  for (int d = 1; d < 1024; d <<= 1) {
    const int u = (t >= d) ? s[t - d] : 0;
    __syncthreads();
    s[t] += u;
    __syncthreads();
  }
  if (i < SCANB_N) boffs[i] = s[t];
  if (t == 1023) partials[blockIdx.x] = s[1023];
}

__global__ __launch_bounds__(1024) void bscanB_kernel(
    int* __restrict__ boffs, const int* __restrict__ partials) {
  __shared__ int sp[256];
  const int t = threadIdx.x;
  if (t < 256) sp[t] = (t < (int)blockIdx.x && t < SCANB_BLOCKS) ? partials[t] : 0;
  __syncthreads();
#pragma unroll
  for (int w = 128; w >= 1; w >>= 1) {
    if (t < w) sp[t] += sp[t + w];
    __syncthreads();
  }
  const int i = blockIdx.x * 1024 + t;
  if (i < SCANB_N) boffs[i] += sp[0];
}

// Scatter edges into bucket-grouped order. Rank comes from LDS cursors
// (re-derived; any enumeration 0..cnt-1 is valid since rows are summed).
__global__ __launch_bounds__(256) void bscatter_kernel(
    const int* __restrict__ rows, const int* __restrict__ cols,
    const float* __restrict__ vals, const int* __restrict__ boffs,
    unsigned* __restrict__ pairs, unsigned char* __restrict__ rowlo) {
  __shared__ int cur[NB];
  const int t = threadIdx.x, blk = blockIdx.x;
  for (int i = t; i < NB; i += 256) cur[i] = boffs[i * NBLK + blk];
  __syncthreads();
  const int base = blk * EPB;
  for (int i = t; i < EPB; i += 256) {
    const int e = base + i;
    const int r = rows[e];
    const int c = cols[e];
    const float v = vals[e];
    const int pos = atomicAdd(&cur[r >> 7], 1);   // LDS atomic only
    const unsigned q = (unsigned)(v * 32767.f + 0.5f);
    pairs[pos] = ((unsigned)c << 15) | q;
    rowlo[pos] = (unsigned char)(r & (BROWS - 1));
  }
}

// Per-bucket counting sort by local row; in-place (bucket staged in LDS
// before any write). Also writes row_start for the bucket's rows.
__global__ __launch_bounds__(256) void rowsort_kernel(
    const int* __restrict__ boffs, unsigned* __restrict__ pairs,
    const unsigned char* __restrict__ rowlo, int* __restrict__ row_start) {
  __shared__ unsigned spair[K4_CAP];
  __shared__ unsigned char srl[K4_CAP];
  __shared__ int rcnt[BROWS];
  __shared__ int rsc[BROWS];
  __shared__ int rpos[BROWS];
  const int b = blockIdx.x, t = threadIdx.x;
  const int bstart = boffs[b * NBLK];
  const int bend = (b == NB - 1) ? N_EDGES : boffs[(b + 1) * NBLK];
  const int cnt = bend - bstart;   // mean 2046; K4_CAP=8192 is +130 sigma

  for (int i = t; i < BROWS; i += 256) rcnt[i] = 0;
  __syncthreads();
  for (int i = t; i < cnt; i += 256) {
    const unsigned p = pairs[bstart + i];
    const unsigned char rl = rowlo[bstart + i];
    spair[i] = p;
    srl[i] = rl;
    atomicAdd(&rcnt[rl], 1);
  }
  __syncthreads();
  // Inclusive scan of rcnt over BROWS entries.
  if (t < BROWS) rsc[t] = rcnt[t];
  __syncthreads();
#pragma unroll
  for (int d = 1; d < BROWS; d <<= 1) {
    int v = 0;
    if (t < BROWS && t >= d) v = rsc[t - d];
    __syncthreads();
    if (t < BROWS) rsc[t] += v;
    __syncthreads();
  }
  const int r0 = b * BROWS;
  const int nrows = min(BROWS, N_NODES - r0);
  if (t < nrows) {
    const int ex = rsc[t] - rcnt[t];      // exclusive prefix
    row_start[r0 + t] = bstart + ex;
    rpos[t] = bstart + ex;                // global write cursor per row
  }
  if (b == NB - 1 && t == 0) row_start[N_NODES] = N_EDGES;
  __syncthreads();
  for (int i = t; i < cnt; i += 256) {
    const int pos = atomicAdd(&rpos[srl[i]], 1);
    pairs[pos] = spair[i];
  }
}

// ---------------------------------------------------------------------------
// Gather: one wave per row. 4 edges processed in parallel (lane groups of 16);
// each group loads its edge's support row as 16 x uint4 = 256 B coalesced.
// ---------------------------------------------------------------------------
__global__ __launch_bounds__(256) void gather_kernel(
    const int* __restrict__ row_start, const unsigned* __restrict__ pairs,
    const uint4* __restrict__ support, const float* __restrict__ bias,
    float* __restrict__ out) {
  const int r = blockIdx.x * 4 + (threadIdx.x >> 6);
  if (r >= N_NODES) return;
  const int lane = threadIdx.x & 63;
  const int g = lane >> 4;        // edge slot 0..3
  const int c16 = lane & 15;      // 16B chunk (8 bf16 cols): cols c16*8..+7
  const int e0 = row_start[r];
  const int e1 = row_start[r + 1];

  float acc[8];
#pragma unroll
  for (int i = 0; i < 8; ++i) acc[i] = 0.f;

  for (int e = e0; e < e1; e += 8) {
    const int ea = e + g;
    const int eb = e + 4 + g;
    const unsigned pa = pairs[min(ea, e1 - 1)];
    const unsigned pb = pairs[min(eb, e1 - 1)];
    const float va = (ea < e1) ? (float)(pa & 0x7FFFu) * (1.f / 32767.f) : 0.f;
    const float vb = (eb < e1) ? (float)(pb & 0x7FFFu) * (1.f / 32767.f) : 0.f;
    const uint4 sa = support[(size_t)(pa >> 15) * 16 + c16];
    const uint4 sb = support[(size_t)(pb >> 15) * 16 + c16];
    acc[0] += va * bflo(sa.x); acc[1] += va * bfhi(sa.x);
    acc[2] += va * bflo(sa.y); acc[3] += va * bfhi(sa.y);
    acc[4] += va * bflo(sa.z); acc[5] += va * bfhi(sa.z);
    acc[6] += va * bflo(sa.w); acc[7] += va * bfhi(sa.w);
    acc[0] += vb * bflo(sb.x); acc[1] += vb * bfhi(sb.x);
    acc[2] += vb * bflo(sb.y); acc[3] += vb * bfhi(sb.y);
    acc[4] += vb * bflo(sb.z); acc[5] += vb * bfhi(sb.z);
    acc[6] += vb * bflo(sb.w); acc[7] += vb * bfhi(sb.w);
  }

#pragma unroll
  for (int i = 0; i < 8; ++i) {
    acc[i] += __shfl_xor(acc[i], 16, 64);
    acc[i] += __shfl_xor(acc[i], 32, 64);
  }

  if (g == 0) {
    const float4 b0 = ((const float4*)bias)[c16 * 2 + 0];
    const float4 b1 = ((const float4*)bias)[c16 * 2 + 1];
    float4 o0, o1;
    o0.x = acc[0] + b0.x; o0.y = acc[1] + b0.y;
    o0.z = acc[2] + b0.z; o0.w = acc[3] + b0.w;
    o1.x = acc[4] + b1.x; o1.y = acc[5] + b1.y;
    o1.z = acc[6] + b1.z; o1.w = acc[7] + b1.w;
    float* op = out + (size_t)r * D + c16 * 8;
    *(float4*)(op + 0) = o0;
    *(float4*)(op + 4) = o1;
  }
}

// ---------------------------------------------------------------------------
// Fallback (atomic path, row-major bf16 support) if workspace too small.
// ---------------------------------------------------------------------------
__global__ __launch_bounds__(256) void init_out_kernel(
    const float* __restrict__ bias, float* __restrict__ out) {
  const size_t idx = (size_t)blockIdx.x * 256 + threadIdx.x;
  const float4 b = ((const float4*)bias)[idx & 31];
  ((float4*)out)[idx] = b;
}

__global__ __launch_bounds__(256) void scatter_kernel(
    const int* __restrict__ rows, const int* __restrict__ cols,
    const float* __restrict__ vals, const uint2* __restrict__ support,
    float* __restrict__ out) {
  const size_t tid = (size_t)blockIdx.x * 256 + threadIdx.x;
  const int e = (int)(tid >> 5);
  const int q = (int)(tid & 31);
  const int r = rows[e];
  const int c = cols[e];
  const float v = vals[e];
  const uint2 s = support[(size_t)c * 32 + q];
  float* o = out + (size_t)r * D + 4 * q;
  atomicAdd(o + 0, v * bflo(s.x));
  atomicAdd(o + 1, v * bfhi(s.x));
  atomicAdd(o + 2, v * bflo(s.y));
  atomicAdd(o + 3, v * bfhi(s.y));
}

extern "C" void kernel_launch(void* const* d_in, const int* in_sizes, int n_in,
                              void* d_out, int out_size, void* d_ws, size_t ws_size,
                              hipStream_t stream) {
  const float* x        = (const float*)d_in[0];
  const float* W        = (const float*)d_in[1];
  const float* lin_bias = (const float*)d_in[2];
  const float* bias     = (const float*)d_in[3];
  const int*   adj_rows = (const int*)d_in[4];
  const int*   adj_cols = (const int*)d_in[5];
  const float* adj_vals = (const float*)d_in[6];
  float* out = (float*)d_out;

  // Workspace layout (16B-aligned offsets):
  //   support   : 25,600,000 B  (N_NODES*D bf16, row-major)
  //   row_start :    400,016 B  (SCAN_N ints, padded)
  //   boffs     :    800,768 B  (NB*NBLK ints)
  //   bcount    :    800,768 B  (NB*NBLK ints)
  //   pairs     :  6,400,000 B  (N_EDGES u32, packed col|q15)
  //   rowlo     :  1,600,000 B  (N_EDGES u8, local row in bucket)
  //   partials  :      1,024 B
  char* wsb = (char*)d_ws;
  unsigned short* support   = (unsigned short*)wsb;
  int*            row_start = (int*)(wsb + 25600000);
  int*            boffs     = (int*)(wsb + 26000016);
  int*            bcount    = (int*)(wsb + 26800784);
  unsigned*       pairs     = (unsigned*)(wsb + 27601552);
  unsigned char*  rowlo     = (unsigned char*)(wsb + 34001552);
  int*            partials  = (int*)(wsb + 35601552);
  const size_t ws_needed = 35602576;

  const bool csr_path = (ws_size >= ws_needed);

  gemm_kernel<<<(N_NODES + GR - 1) / GR, 256, 0, stream>>>(
      x, W, lin_bias, support);

  if (csr_path) {
    bhist_kernel<<<NBLK, 256, 0, stream>>>(adj_rows, bcount);
    bscanA_kernel<<<SCANB_BLOCKS, 1024, 0, stream>>>(bcount, boffs, partials);
    bscanB_kernel<<<SCANB_BLOCKS, 1024, 0, stream>>>(boffs, partials);
    bscatter_kernel<<<NBLK, 256, 0, stream>>>(adj_rows, adj_cols, adj_vals,
                                              boffs, pairs, rowlo);
    rowsort_kernel<<<NB, 256, 0, stream>>>(boffs, pairs, rowlo, row_start);
    gather_kernel<<<(N_NODES + 3) / 4, 256, 0, stream>>>(
        row_start, pairs, (const uint4*)support, bias, out);
  } else {
    init_out_kernel<<<12500, 256, 0, stream>>>(bias, out);
    scatter_kernel<<<200000, 256, 0, stream>>>(adj_rows, adj_cols, adj_vals,
                                               (const uint2*)support, out);
  }
}

// Round 3
// 293.171 us; speedup vs baseline: 1.1286x; 1.0359x over previous
//
#include <hip/hip_runtime.h>
#include <hip/hip_bf16.h>

#define N_NODES 100000
#define N_EDGES 1600000
#define D 128
#define SCAN_N (N_NODES + 1)   // 100001

// Radix-style CSR build parameters
#define NBLK 256                // edge-partition blocks
#define EPB (N_EDGES / NBLK)    // 6250 edges per block
#define BROWS 128               // rows per bucket
#define NB 782                  // ceil(N_NODES / BROWS)
#define SCANB_N (NB * NBLK)     // 200192
#define SCANB_BLOCKS 196        // 196*1024 = 200704 >= SCANB_N + 1
#define K4_CAP 8192             // max staged edges per bucket (mean 2046, +130 sigma)

typedef __attribute__((ext_vector_type(8))) short short8;
typedef __attribute__((ext_vector_type(4))) float f32x4;

__device__ inline unsigned short f2bf(float f) {
  union { float f; unsigned u; } c; c.f = f;
  const unsigned u = c.u;
  return (unsigned short)((u + 0x7FFF + ((u >> 16) & 1)) >> 16);  // RNE
}
__device__ inline float bflo(unsigned u) { return __int_as_float(u << 16); }
__device__ inline float bfhi(unsigned u) { return __int_as_float(u & 0xFFFF0000u); }

// ---------------------------------------------------------------------------
// W pre-transpose: Wt[n][k] = bf16(W[k][n]). One-shot, 16 blocks.
// ---------------------------------------------------------------------------
__global__ __launch_bounds__(256) void wconv_kernel(
    const float* __restrict__ W, unsigned short* __restrict__ Wt) {
  const int t = blockIdx.x * 256 + threadIdx.x;   // 4096 threads
  const int k = t >> 5, n4 = (t & 31) * 4;
  const float4 w = *(const float4*)(W + k * D + n4);
  Wt[(n4 + 0) * D + k] = f2bf(w.x);
  Wt[(n4 + 1) * D + k] = f2bf(w.y);
  Wt[(n4 + 2) * D + k] = f2bf(w.z);
  Wt[(n4 + 3) * D + k] = f2bf(w.w);
}

// ---------------------------------------------------------------------------
// GEMM (bf16 MFMA): support[n][j] = bf16((x@W + lin_bias)[n][j]), row-major.
// 128 rows/block, 256 threads (4 waves). B-fragments from global Wt (L1-hot,
// 32 KB); only x staged in LDS (34.8 KB -> 4 blocks/CU).
// ---------------------------------------------------------------------------
#define GR 128
#define LDK 136
__global__ __launch_bounds__(256) void gemm_kernel(
    const float* __restrict__ x, const unsigned short* __restrict__ Wt,
    const float* __restrict__ lin_bias, unsigned short* __restrict__ support) {
  __shared__ unsigned short xb[GR * LDK];   // xb[r][k]
  const int t = threadIdx.x;
  const int row0 = blockIdx.x * GR;

  for (int i = t; i < GR * 32; i += 256) {
    const int r = i >> 5, k4 = (i & 31) * 4;
    const int row = row0 + r;
    float4 v = make_float4(0.f, 0.f, 0.f, 0.f);
    if (row < N_NODES) v = *(const float4*)(x + (size_t)row * D + k4);
    unsigned short* p = &xb[r * LDK + k4];
    p[0] = f2bf(v.x); p[1] = f2bf(v.y); p[2] = f2bf(v.z); p[3] = f2bf(v.w);
  }
  __syncthreads();

  const int w = t >> 6;
  const int lane = t & 63;
  const int m16 = lane & 15;
  const int quad = lane >> 4;

  f32x4 acc[2][8];
#pragma unroll
  for (int rt = 0; rt < 2; ++rt)
#pragma unroll
    for (int ct = 0; ct < 8; ++ct) acc[rt][ct] = (f32x4){0.f, 0.f, 0.f, 0.f};

#pragma unroll
  for (int kc = 0; kc < 4; ++kc) {
    const int kof = kc * 32 + quad * 8;
    short8 a0 = *(const short8*)&xb[(w * 32 + 0 * 16 + m16) * LDK + kof];
    short8 a1 = *(const short8*)&xb[(w * 32 + 1 * 16 + m16) * LDK + kof];
#pragma unroll
    for (int ct = 0; ct < 8; ++ct) {
      const short8 b = *(const short8*)&Wt[(size_t)(ct * 16 + m16) * D + kof];
      acc[0][ct] = __builtin_amdgcn_mfma_f32_16x16x32_bf16(a0, b, acc[0][ct], 0, 0, 0);
      acc[1][ct] = __builtin_amdgcn_mfma_f32_16x16x32_bf16(a1, b, acc[1][ct], 0, 0, 0);
    }
  }

  // Epilogue: C/D layout col=lane&15, row=quad*4+reg. Row-major bf16 stores.
#pragma unroll
  for (int ct = 0; ct < 8; ++ct) {
    const int col = ct * 16 + m16;
    const float lb = lin_bias[col];
#pragma unroll
    for (int rt = 0; rt < 2; ++rt) {
      const int rbase = row0 + w * 32 + rt * 16 + quad * 4;
#pragma unroll
      for (int i = 0; i < 4; ++i) {
        const int row = rbase + i;
        if (row < N_NODES)
          support[(size_t)row * D + col] = f2bf(acc[rt][ct][i] + lb);
      }
    }
  }
}

// ---------------------------------------------------------------------------
// CSR build, no global atomics (bhist -> bscanA/B -> bscatter -> rowsort).
// ---------------------------------------------------------------------------
__global__ __launch_bounds__(256) void bhist_kernel(
    const int* __restrict__ rows, int* __restrict__ bcount) {
  __shared__ int cnt[NB];
  const int t = threadIdx.x, blk = blockIdx.x;
  for (int i = t; i < NB; i += 256) cnt[i] = 0;
  __syncthreads();
  const int base = blk * EPB;
  for (int i = t; i < EPB; i += 256) {
    const int r = rows[base + i];
    atomicAdd(&cnt[r >> 7], 1);     // LDS atomic only
  }
  __syncthreads();
  for (int i = t; i < NB; i += 256) bcount[i * NBLK + blk] = cnt[i];
}

// Inclusive scan of shifted bcount => exclusive offsets boffs.
__global__ __launch_bounds__(1024) void bscanA_kernel(
    const int* __restrict__ bcount, int* __restrict__ boffs,
    int* __restrict__ partials) {
  __shared__ int s[1024];
  const int t = threadIdx.x;
  const int i = blockIdx.x * 1024 + t;
  int v = 0;
  if (i >= 1 && i <= SCANB_N) v = bcount[i - 1];
  s[t] = v;
  __syncthreads();
#pragma unroll
  for (int d = 1; d < 1024; d <<= 1) {
    const int u = (t >= d) ? s[t - d] : 0;
    __syncthreads();
    s[t] += u;
    __syncthreads();
  }
  if (i < SCANB_N) boffs[i] = s[t];
  if (t == 1023) partials[blockIdx.x] = s[1023];
}

__global__ __launch_bounds__(1024) void bscanB_kernel(
    int* __restrict__ boffs, const int* __restrict__ partials) {
  __shared__ int sp[256];
  const int t = threadIdx.x;
  if (t < 256) sp[t] = (t < (int)blockIdx.x && t < SCANB_BLOCKS) ? partials[t] : 0;
  __syncthreads();
#pragma unroll
  for (int w = 128; w >= 1; w >>= 1) {
    if (t < w) sp[t] += sp[t + w];
    __syncthreads();
  }
  const int i = blockIdx.x * 1024 + t;
  if (i < SCANB_N) boffs[i] += sp[0];
}

// Scatter edges into bucket-grouped order. Rank comes from LDS cursors.
__global__ __launch_bounds__(256) void bscatter_kernel(
    const int* __restrict__ rows, const int* __restrict__ cols,
    const float* __restrict__ vals, const int* __restrict__ boffs,
    unsigned* __restrict__ pairs, unsigned char* __restrict__ rowlo) {
  __shared__ int cur[NB];
  const int t = threadIdx.x, blk = blockIdx.x;
  for (int i = t; i < NB; i += 256) cur[i] = boffs[i * NBLK + blk];
  __syncthreads();
  const int base = blk * EPB;
  for (int i = t; i < EPB; i += 256) {
    const int e = base + i;
    const int r = rows[e];
    const int c = cols[e];
    const float v = vals[e];
    const int pos = atomicAdd(&cur[r >> 7], 1);   // LDS atomic only
    const unsigned q = (unsigned)(v * 32767.f + 0.5f);
    pairs[pos] = ((unsigned)c << 15) | q;
    rowlo[pos] = (unsigned char)(r & (BROWS - 1));
  }
}

// Per-bucket counting sort by local row; in-place. Emits row_start.
__global__ __launch_bounds__(256) void rowsort_kernel(
    const int* __restrict__ boffs, unsigned* __restrict__ pairs,
    const unsigned char* __restrict__ rowlo, int* __restrict__ row_start) {
  __shared__ unsigned spair[K4_CAP];
  __shared__ unsigned char srl[K4_CAP];
  __shared__ int rcnt[BROWS];
  __shared__ int rsc[BROWS];
  __shared__ int rpos[BROWS];
  const int b = blockIdx.x, t = threadIdx.x;
  const int bstart = boffs[b * NBLK];
  const int bend = (b == NB - 1) ? N_EDGES : boffs[(b + 1) * NBLK];
  const int cnt = bend - bstart;   // mean 2046; K4_CAP=8192 is +130 sigma

  for (int i = t; i < BROWS; i += 256) rcnt[i] = 0;
  __syncthreads();
  for (int i = t; i < cnt; i += 256) {
    const unsigned p = pairs[bstart + i];
    const unsigned char rl = rowlo[bstart + i];
    spair[i] = p;
    srl[i] = rl;
    atomicAdd(&rcnt[rl], 1);
  }
  __syncthreads();
  if (t < BROWS) rsc[t] = rcnt[t];
  __syncthreads();
#pragma unroll
  for (int d = 1; d < BROWS; d <<= 1) {
    int v = 0;
    if (t < BROWS && t >= d) v = rsc[t - d];
    __syncthreads();
    if (t < BROWS) rsc[t] += v;
    __syncthreads();
  }
  const int r0 = b * BROWS;
  const int nrows = min(BROWS, N_NODES - r0);
  if (t < nrows) {
    const int ex = rsc[t] - rcnt[t];      // exclusive prefix
    row_start[r0 + t] = bstart + ex;
    rpos[t] = bstart + ex;                // global write cursor per row
  }
  if (b == NB - 1 && t == 0) row_start[N_NODES] = N_EDGES;
  __syncthreads();
  for (int i = t; i < cnt; i += 256) {
    const int pos = atomicAdd(&rpos[srl[i]], 1);
    pairs[pos] = spair[i];
  }
}

// ---------------------------------------------------------------------------
// Gather: one wave per row, 4 edge slots (16 lanes each) x 4-deep unroll
// = 16 edges (4 KB) in flight per wave. Per-row pairs prefetched with ONE
// coalesced load (64 edges/chunk) and broadcast via shfl -- removes the
// pairs->support dependent-load chain from the loop. Tail slots are
// exec-masked (no duplicate clamped loads).
// ---------------------------------------------------------------------------
__global__ __launch_bounds__(256) void gather_kernel(
    const int* __restrict__ row_start, const unsigned* __restrict__ pairs,
    const uint4* __restrict__ support, const float* __restrict__ bias,
    float* __restrict__ out) {
  const int r = blockIdx.x * 4 + (threadIdx.x >> 6);
  if (r >= N_NODES) return;
  const int lane = threadIdx.x & 63;
  const int g = lane >> 4;        // edge slot 0..3
  const int c16 = lane & 15;      // 16B chunk (8 bf16 cols): cols c16*8..+7
  const int e0 = row_start[r];
  const int e1 = row_start[r + 1];
  const int deg = e1 - e0;

  float acc[8];
#pragma unroll
  for (int i = 0; i < 8; ++i) acc[i] = 0.f;

  for (int base = 0; base < deg; base += 64) {
    const int rem = deg - base;
    const int n = (rem < 64) ? rem : 64;
    const unsigned pv = (lane < rem) ? pairs[e0 + base + lane] : 0u;

    for (int it = 0; it < n; it += 16) {
      const int ia = it + g;
      const int ib = it + 4 + g;
      const int ic = it + 8 + g;
      const int id = it + 12 + g;
      const unsigned pa = __shfl(pv, ia, 64);
      const unsigned pb = __shfl(pv, ib, 64);
      const unsigned pc = __shfl(pv, ic, 64);
      const unsigned pd = __shfl(pv, id, 64);
      if (ia < n) {
        const float va = (float)(pa & 0x7FFFu) * (1.f / 32767.f);
        const uint4 sa = support[(size_t)(pa >> 15) * 16 + c16];
        acc[0] += va * bflo(sa.x); acc[1] += va * bfhi(sa.x);
        acc[2] += va * bflo(sa.y); acc[3] += va * bfhi(sa.y);
        acc[4] += va * bflo(sa.z); acc[5] += va * bfhi(sa.z);
        acc[6] += va * bflo(sa.w); acc[7] += va * bfhi(sa.w);
      }
      if (ib < n) {
        const float vb = (float)(pb & 0x7FFFu) * (1.f / 32767.f);
        const uint4 sb = support[(size_t)(pb >> 15) * 16 + c16];
        acc[0] += vb * bflo(sb.x); acc[1] += vb * bfhi(sb.x);
        acc[2] += vb * bflo(sb.y); acc[3] += vb * bfhi(sb.y);
        acc[4] += vb * bflo(sb.z); acc[5] += vb * bfhi(sb.z);
        acc[6] += vb * bflo(sb.w); acc[7] += vb * bfhi(sb.w);
      }
      if (ic < n) {
        const float vc = (float)(pc & 0x7FFFu) * (1.f / 32767.f);
        const uint4 sc = support[(size_t)(pc >> 15) * 16 + c16];
        acc[0] += vc * bflo(sc.x); acc[1] += vc * bfhi(sc.x);
        acc[2] += vc * bflo(sc.y); acc[3] += vc * bfhi(sc.y);
        acc[4] += vc * bflo(sc.z); acc[5] += vc * bfhi(sc.z);
        acc[6] += vc * bflo(sc.w); acc[7] += vc * bfhi(sc.w);
      }
      if (id < n) {
        const float vd = (float)(pd & 0x7FFFu) * (1.f / 32767.f);
        const uint4 sd = support[(size_t)(pd >> 15) * 16 + c16];
        acc[0] += vd * bflo(sd.x); acc[1] += vd * bfhi(sd.x);
        acc[2] += vd * bflo(sd.y); acc[3] += vd * bfhi(sd.y);
        acc[4] += vd * bflo(sd.z); acc[5] += vd * bfhi(sd.z);
        acc[6] += vd * bflo(sd.w); acc[7] += vd * bfhi(sd.w);
      }
    }
  }

  // Fold the 4 edge slots (lanes l, l^16, l^32, l^48 hold the same cols).
#pragma unroll
  for (int i = 0; i < 8; ++i) {
    acc[i] += __shfl_xor(acc[i], 16, 64);
    acc[i] += __shfl_xor(acc[i], 32, 64);
  }

  if (g == 0) {
    const float4 b0 = ((const float4*)bias)[c16 * 2 + 0];
    const float4 b1 = ((const float4*)bias)[c16 * 2 + 1];
    float4 o0, o1;
    o0.x = acc[0] + b0.x; o0.y = acc[1] + b0.y;
    o0.z = acc[2] + b0.z; o0.w = acc[3] + b0.w;
    o1.x = acc[4] + b1.x; o1.y = acc[5] + b1.y;
    o1.z = acc[6] + b1.z; o1.w = acc[7] + b1.w;
    float* op = out + (size_t)r * D + c16 * 8;
    *(float4*)(op + 0) = o0;
    *(float4*)(op + 4) = o1;
  }
}

// ---------------------------------------------------------------------------
// Fallback (atomic path, row-major bf16 support) if workspace too small.
// ---------------------------------------------------------------------------
__global__ __launch_bounds__(256) void init_out_kernel(
    const float* __restrict__ bias, float* __restrict__ out) {
  const size_t idx = (size_t)blockIdx.x * 256 + threadIdx.x;
  const float4 b = ((const float4*)bias)[idx & 31];
  ((float4*)out)[idx] = b;
}

__global__ __launch_bounds__(256) void scatter_kernel(
    const int* __restrict__ rows, const int* __restrict__ cols,
    const float* __restrict__ vals, const uint2* __restrict__ support,
    float* __restrict__ out) {
  const size_t tid = (size_t)blockIdx.x * 256 + threadIdx.x;
  const int e = (int)(tid >> 5);
  const int q = (int)(tid & 31);
  const int r = rows[e];
  const int c = cols[e];
  const float v = vals[e];
  const uint2 s = support[(size_t)c * 32 + q];
  float* o = out + (size_t)r * D + 4 * q;
  atomicAdd(o + 0, v * bflo(s.x));
  atomicAdd(o + 1, v * bfhi(s.x));
  atomicAdd(o + 2, v * bflo(s.y));
  atomicAdd(o + 3, v * bfhi(s.y));
}

extern "C" void kernel_launch(void* const* d_in, const int* in_sizes, int n_in,
                              void* d_out, int out_size, void* d_ws, size_t ws_size,
                              hipStream_t stream) {
  const float* x        = (const float*)d_in[0];
  const float* W        = (const float*)d_in[1];
  const float* lin_bias = (const float*)d_in[2];
  const float* bias     = (const float*)d_in[3];
  const int*   adj_rows = (const int*)d_in[4];
  const int*   adj_cols = (const int*)d_in[5];
  const float* adj_vals = (const float*)d_in[6];
  float* out = (float*)d_out;

  // Workspace layout (16B-aligned offsets):
  //   support   : 25,600,000 B  (N_NODES*D bf16, row-major)
  //   row_start :    400,016 B  (SCAN_N ints, padded)
  //   boffs     :    800,768 B  (NB*NBLK ints)
  //   bcount    :    800,768 B  (NB*NBLK ints)
  //   pairs     :  6,400,000 B  (N_EDGES u32, packed col|q15)
  //   rowlo     :  1,600,000 B  (N_EDGES u8, local row in bucket)
  //   partials  :      1,024 B
  //   wt        :     32,768 B  (128x128 bf16, W transposed)
  char* wsb = (char*)d_ws;
  unsigned short* support   = (unsigned short*)wsb;
  int*            row_start = (int*)(wsb + 25600000);
  int*            boffs     = (int*)(wsb + 26000016);
  int*            bcount    = (int*)(wsb + 26800784);
  unsigned*       pairs     = (unsigned*)(wsb + 27601552);
  unsigned char*  rowlo     = (unsigned char*)(wsb + 34001552);
  int*            partials  = (int*)(wsb + 35601552);
  const size_t ws_needed = 35635344;   // incl. wt at 35602576

  const bool csr_path = (ws_size >= ws_needed);
  // wt: after the CSR arrays on the CSR path; right after support otherwise.
  unsigned short* wt = (unsigned short*)(csr_path ? (wsb + 35602576)
                                                  : (wsb + 25600000));

  wconv_kernel<<<16, 256, 0, stream>>>(W, wt);
  gemm_kernel<<<(N_NODES + GR - 1) / GR, 256, 0, stream>>>(
      x, wt, lin_bias, support);

  if (csr_path) {
    bhist_kernel<<<NBLK, 256, 0, stream>>>(adj_rows, bcount);
    bscanA_kernel<<<SCANB_BLOCKS, 1024, 0, stream>>>(bcount, boffs, partials);
    bscanB_kernel<<<SCANB_BLOCKS, 1024, 0, stream>>>(boffs, partials);
    bscatter_kernel<<<NBLK, 256, 0, stream>>>(adj_rows, adj_cols, adj_vals,
                                              boffs, pairs, rowlo);
    rowsort_kernel<<<NB, 256, 0, stream>>>(boffs, pairs, rowlo, row_start);
    gather_kernel<<<(N_NODES + 3) / 4, 256, 0, stream>>>(
        row_start, pairs, (const uint4*)support, bias, out);
  } else {
    init_out_kernel<<<12500, 256, 0, stream>>>(bias, out);
    scatter_kernel<<<200000, 256, 0, stream>>>(adj_rows, adj_cols, adj_vals,
                                               (const uint2*)support, out);
  }
}